// Round 1
// baseline (197.317 us; speedup 1.0000x reference)
//
#include <hip/hip_runtime.h>
#include <math.h>

// PointLoss: fused masked reduction over B*H*W pixels -> scalar.
// v2: quad-per-thread vectorized streaming + flattened gather batch for MLP.
// Main kernel writes per-block partials to d_ws, finalize reduces in double.

namespace {
constexpr int B_ = 64, H_ = 52, W_ = 720;
constexpr int HW_ = H_ * W_;           // 37440
constexpr int NPIX = B_ * HW_;         // 2396160
constexpr int QPI  = HW_ / 4;          // 9360 quads per image (HW_ % 4 == 0)
constexpr int NQUAD = NPIX / 4;        // 599040
constexpr int NTHREADS = 256;
constexpr int QPT = 2;                 // quads per thread
constexpr int NBLOCKS = NQUAD / (NTHREADS * QPT);   // 1170, all co-resident
constexpr int TQUADS = NBLOCKS * NTHREADS;          // 299520
constexpr float EPSF = 1e-8f;
constexpr float RAD2DEG = 57.29577951308232f;  // 180/pi
}
static_assert(NBLOCKS * NTHREADS * QPT == NQUAD, "grid must tile quads exactly");

__global__ __launch_bounds__(NTHREADS) void pointloss_main(
    const float* __restrict__ v,      // vertexmap_proj   [B,H,W,3]
    const float* __restrict__ nrm,    // normalmap_proj   [B,H,W,3]
    const float* __restrict__ unc,    // uncertainty      [B,H,W]
    const float* __restrict__ nown,   // now_normalmap    [B,H,W,3]
    const float* __restrict__ conf,   // now_confidencemap[B,H,W]
    const float* __restrict__ lastn,  // last_normalmap   [B,H,W,3]
    const float* __restrict__ lastv,  // last_vertexmap   [B,H,W,3]
    const int*   __restrict__ nowm,   // now_maskmap      [B,H,W]
    const int*   __restrict__ lastm,  // last_maskmap     [B,H,W]
    float* __restrict__ partials)     // [NBLOCKS*5]
{
    float s_m0 = 0.f, s_fov = 0.f, s_m = 0.f, s_icp = 0.f, s_ang = 0.f;

    const float4* __restrict__ v4 = (const float4*)v;
    const float4* __restrict__ n4 = (const float4*)nown;
    const int4*   __restrict__ m4 = (const int4*)nowm;
    const float4* __restrict__ c4 = (const float4*)conf;

    const int tid = blockIdx.x * NTHREADS + threadIdx.x;

    #pragma unroll
    for (int it = 0; it < QPT; ++it) {
        const int q  = tid + it * TQUADS;
        const int p0 = q * 4;
        const int gbase = (q / QPI) * HW_;   // image base (quads never straddle images)

        // --- vectorized streaming loads: 8 dwordx4 per quad ---
        const float4 va = v4[3*q+0], vb = v4[3*q+1], vc = v4[3*q+2];
        const float4 na = n4[3*q+0], nb = n4[3*q+1], nc = n4[3*q+2];
        const int4   mm = m4[q];
        const float4 cf = c4[q];

        const float vx[4] = {va.x, va.w, vb.z, vc.y};
        const float vy[4] = {va.y, vb.x, vb.w, vc.z};
        const float vz[4] = {va.z, vb.y, vc.x, vc.w};
        const float ax[4] = {na.x, na.w, nb.z, nc.y};
        const float ay[4] = {na.y, nb.x, nb.w, nc.z};
        const float az[4] = {na.z, nb.y, nc.x, nc.w};
        const int   mk[4] = {mm.x, mm.y, mm.z, mm.w};
        const float cv[4] = {cf.x, cf.y, cf.z, cf.w};

        // --- phase 1: projection math, fov loss, gather predicates ---
        bool g[4];
        int  gi[4];
        #pragma unroll
        for (int j = 0; j < 4; ++j) {
            const bool mask0 = (mk[j] > 0) &&
                ((fabsf(ax[j]) + fabsf(ay[j]) + fabsf(az[j])) != 0.0f);

            const float depth = sqrtf(vx[j]*vx[j] + vy[j]*vy[j] + vz[j]*vz[j] + EPSF);
            const float yaw   = atan2f(vy[j], vx[j]) * RAD2DEG;
            const float pitch = asinf(fminf(fmaxf(vz[j] / depth, -1.f), 1.f)) * RAD2DEG;
            const float px = (180.0f - yaw) * 2.0f;   // /DH with DH=0.5
            const float py = (3.0f - pitch) * 2.0f;   // /DV with DV=0.5

            if (mask0) {
                const float dx = px - fminf(fmaxf(px, 0.f), (float)(W_ - 1));
                const float dy = py - fminf(fmaxf(py, 0.f), (float)(H_ - 1));
                s_m0  += 1.0f;
                s_fov += dx*dx + dy*dy;
            }

            // jnp.round = round-half-even -> rintf (v_rndne_f32)
            const float prx = rintf(px), pry = rintf(py);
            const bool inb = (prx >= 0.f) && (prx < (float)W_) &&
                             (pry >= 0.f) && (pry < (float)H_);
            g[j]  = mask0 && inb && (cv[j] >= 0.5f);
            gi[j] = g[j] ? (gbase + (int)pry * W_ + (int)prx) : 0;
        }

        // --- phase 2: issue ALL gather-path loads in one batch (load-only) ---
        float lx[4] = {0,0,0,0}, ly[4] = {0,0,0,0}, lz[4] = {0,0,0,0};
        float wx[4] = {0,0,0,0}, wy[4] = {0,0,0,0}, wz[4] = {0,0,0,0};
        float nx[4] = {0,0,0,0}, ny[4] = {0,0,0,0}, nz[4] = {0,0,0,0};
        float uu[4] = {0,0,0,0};
        int   lm[4] = {0,0,0,0};
        #pragma unroll
        for (int j = 0; j < 4; ++j) {
            if (g[j]) {
                const int gi3 = 3 * gi[j];
                const int p   = p0 + j;
                lx[j] = lastn[gi3+0]; ly[j] = lastn[gi3+1]; lz[j] = lastn[gi3+2];
                lm[j] = lastm[gi[j]];
                wx[j] = lastv[gi3+0]; wy[j] = lastv[gi3+1]; wz[j] = lastv[gi3+2];
                nx[j] = nrm[3*p+0];   ny[j] = nrm[3*p+1];   nz[j] = nrm[3*p+2];
                uu[j] = unc[p];
            }
        }

        // --- phase 3: consume ---
        #pragma unroll
        for (int j = 0; j < 4; ++j) {
            if (g[j] && (lm[j] > 0) &&
                ((fabsf(lx[j]) + fabsf(ly[j]) + fabsf(lz[j])) != 0.f)) {
                const float r  = lx[j]*(vx[j]-wx[j]) + ly[j]*(vy[j]-wy[j])
                               + lz[j]*(vz[j]-wz[j]);
                const float dt = lx[j]*nx[j] + ly[j]*ny[j] + lz[j]*nz[j];
                const float den = (lx[j]*lx[j] + ly[j]*ly[j] + lz[j]*lz[j]) *
                                  (nx[j]*nx[j] + ny[j]*ny[j] + nz[j]*nz[j]) + EPSF;
                const float cosang = fabsf(dt) * rsqrtf(den);
                s_m   += 1.0f;
                s_icp += uu[j] * fabsf(r);
                s_ang += uu[j] * (1.0f - cosang);
            }
        }
    }

    // wave64 shuffle reduce
    #pragma unroll
    for (int off = 32; off > 0; off >>= 1) {
        s_m0  += __shfl_down(s_m0,  off);
        s_fov += __shfl_down(s_fov, off);
        s_m   += __shfl_down(s_m,   off);
        s_icp += __shfl_down(s_icp, off);
        s_ang += __shfl_down(s_ang, off);
    }
    __shared__ float red[NTHREADS / 64][5];
    const int lane = threadIdx.x & 63;
    const int wv   = threadIdx.x >> 6;
    if (lane == 0) {
        red[wv][0] = s_m0;  red[wv][1] = s_fov; red[wv][2] = s_m;
        red[wv][3] = s_icp; red[wv][4] = s_ang;
    }
    __syncthreads();
    if (threadIdx.x == 0) {
        float t[5] = {0.f, 0.f, 0.f, 0.f, 0.f};
        for (int w2 = 0; w2 < NTHREADS / 64; ++w2)
            for (int c = 0; c < 5; ++c) t[c] += red[w2][c];
        float* o = partials + blockIdx.x * 5;
        for (int c = 0; c < 5; ++c) o[c] = t[c];
    }
}

__global__ __launch_bounds__(256) void pointloss_finalize(
    const float* __restrict__ partials,
    const float* __restrict__ sx,
    const float* __restrict__ sq,
    float* __restrict__ out)
{
    double a0 = 0, a1 = 0, a2 = 0, a3 = 0, a4 = 0;
    for (int i = threadIdx.x; i < NBLOCKS; i += 256) {
        const float* pp = partials + i * 5;
        a0 += (double)pp[0]; a1 += (double)pp[1]; a2 += (double)pp[2];
        a3 += (double)pp[3]; a4 += (double)pp[4];
    }
    #pragma unroll
    for (int off = 32; off > 0; off >>= 1) {
        a0 += __shfl_down(a0, off);
        a1 += __shfl_down(a1, off);
        a2 += __shfl_down(a2, off);
        a3 += __shfl_down(a3, off);
        a4 += __shfl_down(a4, off);
    }
    __shared__ double red[4][5];
    const int lane = threadIdx.x & 63;
    const int wv   = threadIdx.x >> 6;
    if (lane == 0) {
        red[wv][0] = a0; red[wv][1] = a1; red[wv][2] = a2;
        red[wv][3] = a3; red[wv][4] = a4;
    }
    __syncthreads();
    if (threadIdx.x == 0) {
        double t[5] = {0, 0, 0, 0, 0};
        for (int w2 = 0; w2 < 4; ++w2)
            for (int c = 0; c < 5; ++c) t[c] += red[w2][c];
        const double n0 = fmax(t[0], 1.0);
        const double n  = fmax(t[2], 1.0);
        const double sx0 = (double)sx[0], sq0 = (double)sq[0];
        const double total = exp(-sx0) * (t[3] / n) + sx0
                           + exp(-sq0) * (t[4] / n) + sq0
                           + t[1] / n0;   // LAMDA = 1, ANGRATE = 1
        out[0] = (float)total;
    }
}

extern "C" void kernel_launch(void* const* d_in, const int* in_sizes, int n_in,
                              void* d_out, int out_size, void* d_ws, size_t ws_size,
                              hipStream_t stream) {
    const float* v     = (const float*)d_in[0];
    const float* nrm   = (const float*)d_in[1];
    const float* unc   = (const float*)d_in[2];
    const float* nown  = (const float*)d_in[3];
    const float* conf  = (const float*)d_in[4];
    const float* lastn = (const float*)d_in[5];
    const float* lastv = (const float*)d_in[6];
    const float* sx    = (const float*)d_in[7];
    const float* sq    = (const float*)d_in[8];
    const int*   nowm  = (const int*)d_in[9];
    const int*   lastm = (const int*)d_in[10];

    float* partials = (float*)d_ws;  // NBLOCKS*5 floats = 23.4 KB

    pointloss_main<<<NBLOCKS, NTHREADS, 0, stream>>>(
        v, nrm, unc, nown, conf, lastn, lastv, nowm, lastm, partials);
    pointloss_finalize<<<1, 256, 0, stream>>>(partials, sx, sq, (float*)d_out);
}

// Round 2
// 197.308 us; speedup vs baseline: 1.0000x; 1.0000x over previous
//
#include <hip/hip_runtime.h>
#include <math.h>

// PointLoss: fused masked reduction over B*H*W pixels -> scalar.
// v3: quad-per-thread (1 quad each, exact tiling, 2340 blocks -> CUs stay
// oversubscribed and refilled) + vectorized streaming + single flattened
// gather batch. Main kernel writes per-block partials, finalize reduces.

namespace {
constexpr int B_ = 64, H_ = 52, W_ = 720;
constexpr int HW_ = H_ * W_;           // 37440
constexpr int NPIX = B_ * HW_;         // 2396160
constexpr int QPI  = HW_ / 4;          // 9360 quads per image (HW_ % 4 == 0)
constexpr int NQUAD = NPIX / 4;        // 599040
constexpr int NTHREADS = 256;
constexpr int NBLOCKS = NQUAD / NTHREADS;   // 2340 exactly, 1 quad/thread
constexpr float EPSF = 1e-8f;
constexpr float RAD2DEG = 57.29577951308232f;  // 180/pi
}
static_assert(NBLOCKS * NTHREADS == NQUAD, "grid must tile quads exactly");

__global__ __launch_bounds__(NTHREADS) void pointloss_main(
    const float* __restrict__ v,      // vertexmap_proj   [B,H,W,3]
    const float* __restrict__ nrm,    // normalmap_proj   [B,H,W,3]
    const float* __restrict__ unc,    // uncertainty      [B,H,W]
    const float* __restrict__ nown,   // now_normalmap    [B,H,W,3]
    const float* __restrict__ conf,   // now_confidencemap[B,H,W]
    const float* __restrict__ lastn,  // last_normalmap   [B,H,W,3]
    const float* __restrict__ lastv,  // last_vertexmap   [B,H,W,3]
    const int*   __restrict__ nowm,   // now_maskmap      [B,H,W]
    const int*   __restrict__ lastm,  // last_maskmap     [B,H,W]
    float* __restrict__ partials)     // [NBLOCKS*5]
{
    float s_m0 = 0.f, s_fov = 0.f, s_m = 0.f, s_icp = 0.f, s_ang = 0.f;

    const float4* __restrict__ v4 = (const float4*)v;
    const float4* __restrict__ n4 = (const float4*)nown;
    const float4* __restrict__ r4 = (const float4*)nrm;
    const float4* __restrict__ u4 = (const float4*)unc;
    const int4*   __restrict__ m4 = (const int4*)nowm;
    const float4* __restrict__ c4 = (const float4*)conf;

    const int q  = blockIdx.x * NTHREADS + threadIdx.x;   // < NQUAD always
    const int gbase = (q / QPI) * HW_;   // image base (quads never straddle images)

    // --- vectorized streaming loads: 8 dwordx4 per quad ---
    const float4 va = v4[3*q+0], vb = v4[3*q+1], vc = v4[3*q+2];
    const float4 na = n4[3*q+0], nb = n4[3*q+1], nc = n4[3*q+2];
    const int4   mm = m4[q];
    const float4 cf = c4[q];

    const float vx[4] = {va.x, va.w, vb.z, vc.y};
    const float vy[4] = {va.y, vb.x, vb.w, vc.z};
    const float vz[4] = {va.z, vb.y, vc.x, vc.w};
    const float ax[4] = {na.x, na.w, nb.z, nc.y};
    const float ay[4] = {na.y, nb.x, nb.w, nc.z};
    const float az[4] = {na.z, nb.y, nc.x, nc.w};
    const int   mk[4] = {mm.x, mm.y, mm.z, mm.w};
    const float cv[4] = {cf.x, cf.y, cf.z, cf.w};

    // --- phase 1: projection math, fov loss, gather predicates ---
    bool g[4];
    int  gi[4];
    #pragma unroll
    for (int j = 0; j < 4; ++j) {
        const bool mask0 = (mk[j] > 0) &&
            ((fabsf(ax[j]) + fabsf(ay[j]) + fabsf(az[j])) != 0.0f);

        const float depth = sqrtf(vx[j]*vx[j] + vy[j]*vy[j] + vz[j]*vz[j] + EPSF);
        const float yaw   = atan2f(vy[j], vx[j]) * RAD2DEG;
        const float pitch = asinf(fminf(fmaxf(vz[j] / depth, -1.f), 1.f)) * RAD2DEG;
        const float px = (180.0f - yaw) * 2.0f;   // /DH with DH=0.5
        const float py = (3.0f - pitch) * 2.0f;   // /DV with DV=0.5

        if (mask0) {
            const float dx = px - fminf(fmaxf(px, 0.f), (float)(W_ - 1));
            const float dy = py - fminf(fmaxf(py, 0.f), (float)(H_ - 1));
            s_m0  += 1.0f;
            s_fov += dx*dx + dy*dy;
        }

        // jnp.round = round-half-even -> rintf (v_rndne_f32)
        const float prx = rintf(px), pry = rintf(py);
        const bool inb = (prx >= 0.f) && (prx < (float)W_) &&
                         (pry >= 0.f) && (pry < (float)H_);
        g[j]  = mask0 && inb && (cv[j] >= 0.5f);
        gi[j] = g[j] ? (gbase + (int)pry * W_ + (int)prx) : 0;
    }
    const bool anyg = g[0] | g[1] | g[2] | g[3];

    // --- phase 2: issue ALL gather-path loads in one batch (load-only) ---
    // current-pixel operands are quad-contiguous -> vector loads
    float4 ra = {0,0,0,0}, rb = {0,0,0,0}, rc = {0,0,0,0}, uq = {0,0,0,0};
    if (anyg) {
        ra = r4[3*q+0]; rb = r4[3*q+1]; rc = r4[3*q+2];
        uq = u4[q];
    }
    float lx[4] = {0,0,0,0}, ly[4] = {0,0,0,0}, lz[4] = {0,0,0,0};
    float wx[4] = {0,0,0,0}, wy[4] = {0,0,0,0}, wz[4] = {0,0,0,0};
    int   lm[4] = {0,0,0,0};
    #pragma unroll
    for (int j = 0; j < 4; ++j) {
        if (g[j]) {
            const int gi3 = 3 * gi[j];
            lx[j] = lastn[gi3+0]; ly[j] = lastn[gi3+1]; lz[j] = lastn[gi3+2];
            lm[j] = lastm[gi[j]];
            wx[j] = lastv[gi3+0]; wy[j] = lastv[gi3+1]; wz[j] = lastv[gi3+2];
        }
    }

    const float nx[4] = {ra.x, ra.w, rb.z, rc.y};
    const float ny[4] = {ra.y, rb.x, rb.w, rc.z};
    const float nz[4] = {ra.z, rb.y, rc.x, rc.w};
    const float uu[4] = {uq.x, uq.y, uq.z, uq.w};

    // --- phase 3: consume ---
    #pragma unroll
    for (int j = 0; j < 4; ++j) {
        if (g[j] && (lm[j] > 0) &&
            ((fabsf(lx[j]) + fabsf(ly[j]) + fabsf(lz[j])) != 0.f)) {
            const float r  = lx[j]*(vx[j]-wx[j]) + ly[j]*(vy[j]-wy[j])
                           + lz[j]*(vz[j]-wz[j]);
            const float dt = lx[j]*nx[j] + ly[j]*ny[j] + lz[j]*nz[j];
            const float den = (lx[j]*lx[j] + ly[j]*ly[j] + lz[j]*lz[j]) *
                              (nx[j]*nx[j] + ny[j]*ny[j] + nz[j]*nz[j]) + EPSF;
            const float cosang = fabsf(dt) * rsqrtf(den);
            s_m   += 1.0f;
            s_icp += uu[j] * fabsf(r);
            s_ang += uu[j] * (1.0f - cosang);
        }
    }

    // wave64 shuffle reduce
    #pragma unroll
    for (int off = 32; off > 0; off >>= 1) {
        s_m0  += __shfl_down(s_m0,  off);
        s_fov += __shfl_down(s_fov, off);
        s_m   += __shfl_down(s_m,   off);
        s_icp += __shfl_down(s_icp, off);
        s_ang += __shfl_down(s_ang, off);
    }
    __shared__ float red[NTHREADS / 64][5];
    const int lane = threadIdx.x & 63;
    const int wv   = threadIdx.x >> 6;
    if (lane == 0) {
        red[wv][0] = s_m0;  red[wv][1] = s_fov; red[wv][2] = s_m;
        red[wv][3] = s_icp; red[wv][4] = s_ang;
    }
    __syncthreads();
    if (threadIdx.x == 0) {
        float t[5] = {0.f, 0.f, 0.f, 0.f, 0.f};
        for (int w2 = 0; w2 < NTHREADS / 64; ++w2)
            for (int c = 0; c < 5; ++c) t[c] += red[w2][c];
        float* o = partials + blockIdx.x * 5;
        for (int c = 0; c < 5; ++c) o[c] = t[c];
    }
}

__global__ __launch_bounds__(256) void pointloss_finalize(
    const float* __restrict__ partials,
    const float* __restrict__ sx,
    const float* __restrict__ sq,
    float* __restrict__ out)
{
    double a0 = 0, a1 = 0, a2 = 0, a3 = 0, a4 = 0;
    for (int i = threadIdx.x; i < NBLOCKS; i += 256) {
        const float* pp = partials + i * 5;
        a0 += (double)pp[0]; a1 += (double)pp[1]; a2 += (double)pp[2];
        a3 += (double)pp[3]; a4 += (double)pp[4];
    }
    #pragma unroll
    for (int off = 32; off > 0; off >>= 1) {
        a0 += __shfl_down(a0, off);
        a1 += __shfl_down(a1, off);
        a2 += __shfl_down(a2, off);
        a3 += __shfl_down(a3, off);
        a4 += __shfl_down(a4, off);
    }
    __shared__ double red[4][5];
    const int lane = threadIdx.x & 63;
    const int wv   = threadIdx.x >> 6;
    if (lane == 0) {
        red[wv][0] = a0; red[wv][1] = a1; red[wv][2] = a2;
        red[wv][3] = a3; red[wv][4] = a4;
    }
    __syncthreads();
    if (threadIdx.x == 0) {
        double t[5] = {0, 0, 0, 0, 0};
        for (int w2 = 0; w2 < 4; ++w2)
            for (int c = 0; c < 5; ++c) t[c] += red[w2][c];
        const double n0 = fmax(t[0], 1.0);
        const double n  = fmax(t[2], 1.0);
        const double sx0 = (double)sx[0], sq0 = (double)sq[0];
        const double total = exp(-sx0) * (t[3] / n) + sx0
                           + exp(-sq0) * (t[4] / n) + sq0
                           + t[1] / n0;   // LAMDA = 1, ANGRATE = 1
        out[0] = (float)total;
    }
}

extern "C" void kernel_launch(void* const* d_in, const int* in_sizes, int n_in,
                              void* d_out, int out_size, void* d_ws, size_t ws_size,
                              hipStream_t stream) {
    const float* v     = (const float*)d_in[0];
    const float* nrm   = (const float*)d_in[1];
    const float* unc   = (const float*)d_in[2];
    const float* nown  = (const float*)d_in[3];
    const float* conf  = (const float*)d_in[4];
    const float* lastn = (const float*)d_in[5];
    const float* lastv = (const float*)d_in[6];
    const float* sx    = (const float*)d_in[7];
    const float* sq    = (const float*)d_in[8];
    const int*   nowm  = (const int*)d_in[9];
    const int*   lastm = (const int*)d_in[10];

    float* partials = (float*)d_ws;  // NBLOCKS*5 floats = 46.8 KB

    pointloss_main<<<NBLOCKS, NTHREADS, 0, stream>>>(
        v, nrm, unc, nown, conf, lastn, lastv, nowm, lastm, partials);
    pointloss_finalize<<<1, 256, 0, stream>>>(partials, sx, sq, (float*)d_out);
}